// Round 6
// baseline (718.286 us; speedup 1.0000x reference)
//
#include <hip/hip_runtime.h>
#include <hip/hip_bf16.h>

typedef unsigned short u16;
typedef unsigned int   u32;

#define COUT 128
#define KNB  27

typedef __attribute__((ext_vector_type(8))) __bf16 bf16x8;
typedef __attribute__((ext_vector_type(4))) float  f32x4;

// Stats / BN params / dtype flags / bf16 weights in device globals.
// NOTE: device symbols must NEVER be passed as host-side kernel args
// (host shadow address != device address -> GPU fault). Select via template.
__device__ float g_sum[2][128], g_sq[2][128];
__device__ float g_colsum[64], g_G[4096];
__device__ float g_sc[3][128], g_sh[3][128];
__device__ int   g_f32;   // 1 if float input tensors are fp32, 0 if bf16
__device__ int   g_i64;   // 1 if nbr is int64 (read as int32 pairs)
__device__ __attribute__((aligned(16))) u16 g_W1t[KNB * 128 * 64];   // [k][d][c] bf16
__device__ __attribute__((aligned(16))) u16 g_W2t[KNB * 128 * 128];  // [k][d][c] bf16

__device__ __forceinline__ float b2f(u32 u) {
    union { float f; u32 i; } v; v.i = u << 16; return v.f;
}
__device__ __forceinline__ u16 f2b(float f) {
    union { float f; u32 i; } v; v.f = f;
    u32 r = v.i + 0x7fffu + ((v.i >> 16) & 1u);
    return (u16)(r >> 16);
}
__device__ __forceinline__ float ldf(const void* p, int i, bool f32) {
    return f32 ? ((const float*)p)[i] : b2f((u32)((const u16*)p)[i]);
}

// async 16B global->LDS (DMA, no VGPR round-trip). LDS dest: wave-uniform
// base; HW writes lane l's 16B at base + l*16. Global src is per-lane.
__device__ __forceinline__ void gld16(const void* g, void* l) {
    __builtin_amdgcn_global_load_lds(
        (const __attribute__((address_space(1))) u32*)g,
        (__attribute__((address_space(3))) u32*)l, 16, 0, 0);
}

// Raw LDS-only barrier: waits own ds ops, does NOT drain vmcnt.
__device__ __forceinline__ void lds_sync() {
    asm volatile("s_waitcnt lgkmcnt(0)" ::: "memory");
    __builtin_amdgcn_s_barrier();
    asm volatile("" ::: "memory");
}

__global__ void probe_zero_kernel(const u16* __restrict__ g1w, const int* __restrict__ nbr)
{
    int t = threadIdx.x;
    if (t == 0) {
        g_f32 = (g1w[0] == 0) ? 1 : 0;   // fp32 1.0f low word == 0
        g_i64 = ((nbr[1] | nbr[3] | nbr[5] | nbr[7]) == 0) ? 1 : 0;
    }
    for (int i = t; i < 128; i += 256) {
        g_sum[0][i] = 0.f; g_sq[0][i] = 0.f;
        g_sum[1][i] = 0.f; g_sq[1][i] = 0.f;
    }
    for (int i = t; i < 64; i += 256) g_colsum[i] = 0.f;
    for (int i = t; i < 4096; i += 256) g_G[i] = 0.f;
}

// Transpose+convert W1/W2 (fp32 or bf16 [k][c][d]) -> bf16 [k][d][c] globals,
// and convert x -> bf16 row-major scratch (so conv1 staging is a pure copy).
__global__ void convert_w_kernel(const void* __restrict__ W1, const void* __restrict__ W2,
                                 const void* __restrict__ x, u16* __restrict__ xb, int N)
{
    const bool f32 = (g_f32 != 0);
    const int total1 = KNB * 64 * 128;
    const int total2 = KNB * 128 * 128;
    const int stride = gridDim.x * 256;
    for (int e = blockIdx.x * 256 + threadIdx.x; e < total1 + total2; e += stride) {
        if (e < total1) {
            int k = e / (64 * 128), r = e % (64 * 128);
            int c = r / 128, d = r % 128;
            g_W1t[(k * 128 + d) * 64 + c] = f2b(ldf(W1, e, f32));
        } else {
            int e2 = e - total1;
            int k = e2 / (128 * 128), r = e2 % (128 * 128);
            int c = r / 128, d = r % 128;
            g_W2t[(k * 128 + d) * 128 + c] = f2b(ldf(W2, e2, f32));
        }
    }
    const int totalx4 = (N * 64) / 4;
    for (int e = blockIdx.x * 256 + threadIdx.x; e < totalx4; e += stride) {
        if (f32) {
            float4 v = ((const float4*)x)[e];
            ushort4 r;
            r.x = f2b(v.x); r.y = f2b(v.y); r.z = f2b(v.z); r.w = f2b(v.w);
            ((ushort4*)xb)[e] = r;
        } else {
            ((uint2*)xb)[e] = ((const uint2*)x)[e];
        }
    }
}

// In-place bn1+relu on tmp [N][128] bf16 so conv2's A-staging is a pure copy.
__global__ __launch_bounds__(256)
void bn_relu_kernel(u16* __restrict__ tmp, int N)
{
    const int t  = threadIdx.x;
    const int c0 = (t & 15) * 8;          // stride is a multiple of 16 granules
    float sc[8], sh[8];
#pragma unroll
    for (int j = 0; j < 8; ++j) { sc[j] = g_sc[0][c0 + j]; sh[j] = g_sh[0][c0 + j]; }
    const int total = N * (COUT / 8);
    for (int e = blockIdx.x * 256 + t; e < total; e += gridDim.x * 256) {
        uint4 u = ((const uint4*)tmp)[e];
        float v[8] = { b2f(u.x & 0xffffu), b2f(u.x >> 16),
                       b2f(u.y & 0xffffu), b2f(u.y >> 16),
                       b2f(u.z & 0xffffu), b2f(u.z >> 16),
                       b2f(u.w & 0xffffu), b2f(u.w >> 16) };
#pragma unroll
        for (int j = 0; j < 8; ++j) v[j] = fmaxf(fmaf(v[j], sc[j], sh[j]), 0.f);
        uint4 o;
        o.x = (u32)f2b(v[0]) | ((u32)f2b(v[1]) << 16);
        o.y = (u32)f2b(v[2]) | ((u32)f2b(v[3]) << 16);
        o.z = (u32)f2b(v[4]) | ((u32)f2b(v[5]) << 16);
        o.w = (u32)f2b(v[6]) | ((u32)f2b(v[7]) << 16);
        ((uint4*)tmp)[e] = o;
    }
}

// MFMA gather-conv v6 — r5 skeleton + depth-2 A prefetch (ring-3):
//   BM=128 x BN=128, 4 waves, 64-ch steps; A slabs = 128B full-line gather
//   requests (XOR-pre-swizzled source, swizzled ds_read, linear DMA dest).
//   A: ring-3 LDS (3 x 16KB), DMA issued TWO steps ahead -> per wave 8
//      A-DMAs (64 lines) in flight, 2x round-5's MLP.
//   B: double-buffered DMA (2 x 16KB), issued one step ahead (L2-resident).
//   idx: per-lane global dword loads (L1-resident), inside the vmcnt ledger;
//      issue order pinned with zero-cost asm fences.
// vmcnt ledger (per wave, steady state; region s issues, in pinned order,
// [B(s+1) x4][A(s+2) x4][idx(s+4) x4]):
//   newer-than-B(s) = A(s+1)4 + idx(s+3)4 + B(s+1)4 + A(s+2)4 + idx(s+4)4
//   = 20 -> s_waitcnt vmcnt(20); A(s) is older than B(s) (prologue issues
//   B-first to preserve this for region 0) so it drains too. Tail regions
//   keep issuing clamped DMAs (ledger constant, MFMA skipped); one final
//   vmcnt(0) before the epilogue reuses LDS.
// Loop unrolled x6 (lcm of ring-3 / db-2) -> all buffer and idx-set
// indices are compile-time constants (no scratch, rule #20).
// LDS: A 48KB + B 32KB = 80KB exactly -> 2 blocks/CU.
template<int CIN, bool OUTF32, int WSEL, int SSEL>
__global__ __launch_bounds__(256, 2)
void spconv_mfma(const u16* __restrict__ src, const int* __restrict__ nbr,
                 void* __restrict__ outv, int N)
{
    constexpr int CHUNKS = CIN / 64;            // 1 (conv1) / 2 (conv2)
    constexpr int STEPS  = KNB * CHUNKS;        // 27 / 54
    const u16* __restrict__ Wt = (WSEL == 1) ? g_W1t : g_W2t;

    __shared__ __attribute__((aligned(16))) u16 As[3 * 8192];  // ring-3, 48KB
    __shared__ __attribute__((aligned(16))) u16 Bs[2 * 8192];  // db,     32KB

    const int t    = threadIdx.x;
    const int lane = t & 63;
    const int w    = t >> 6;
    const int mh   = lane & 15;        // fragment row-within-tile / B d-row
    const int qh   = lane >> 4;        // fragment 16B channel slice (0..3)
    const int wm   = w >> 1;           // MFMA row-half (mtiles wm*4..+3)
    const int wn   = w & 1;            // MFMA col-half (ntiles wn*4..+3)
    const int n0   = blockIdx.x * 128;
    const int kst  = (g_i64 != 0) ? 2 : 1;

    // A-DMA lane map: row group r8 = lane>>3, granule = lane&7 (XOR-preswz)
    const int r8   = lane >> 3;
    const int gaw  = ((lane & 7) ^ (r8 & 7)) * 8;   // src granule offset (u16)

    // per-lane nbr bases for this wave's 4 staged row-groups
    u32 nb[4];
#pragma unroll
    for (int j = 0; j < 4; ++j) {
        int gr  = n0 + w * 32 + j * 8 + r8;
        int grc = (gr < N) ? gr : (N - 1);
        nb[j] = (u32)grc * (u32)(KNB * kst);
    }

    // swizzled A fragment read offsets (u16 units), per (kstep, mtile)
    int aoff[2][4];
#pragma unroll
    for (int mt = 0; mt < 4; ++mt) {
        int rr   = wm * 64 + mt * 16 + mh;          // block row of this frag
        int base = (rr >> 3) * 512 + (rr & 7) * 64;
        aoff[0][mt] = base + ((qh       ^ (mh & 7)) * 8);
        aoff[1][mt] = base + (((4 + qh) ^ (mh & 7)) * 8);
    }

    f32x4 acc[4][4];
#pragma unroll
    for (int a = 0; a < 4; ++a)
#pragma unroll
        for (int b = 0; b < 4; ++b) acc[a][b] = (f32x4){0.f, 0.f, 0.f, 0.f};

    int ix[3][4];    // idx set for step S lives in ix[S % 3]

#define KOFC(S) ((CHUNKS == 2) ? ((S) >> 1) : (S))
#define CBC(S)  ((CHUNKS == 2) ? (((S) & 1) * 64) : 0)

    // 4 per-lane idx dword loads (L1-resident; ledger-counted)
#define IDXLD(DST, S) do { \
    int kk_ = KOFC(S); if (kk_ > KNB - 1) kk_ = KNB - 1; \
    _Pragma("unroll") \
    for (int j_ = 0; j_ < 4; ++j_) \
        DST[j_] = (int)nbr[nb[j_] + (u32)kk_ * (u32)kst]; \
} while (0)

    // 4 A-DMAs: 8 rows x 128B each (full-line requests), XOR-preswz source
#define ISSUE_A(ABUF, IDX, S) do { \
    const int cb_ = CBC(S); \
    _Pragma("unroll") \
    for (int j_ = 0; j_ < 4; ++j_) { \
        u32 r_ = (u32)(IDX)[j_]; if (r_ >= (u32)N) r_ = 0; \
        gld16(src + (size_t)r_ * CIN + cb_ + gaw, \
              &As[(ABUF) * 8192 + (w * 4 + j_) * 512]); \
    } \
} while (0)

    // 4 B-DMAs (weight slabs; L2-resident after first pass)
#define ISSUE_B(BBUF, S) do { \
    int kk_ = KOFC(S); if (kk_ > KNB - 1) kk_ = KNB - 1; \
    const int cb_ = CBC(S); \
    _Pragma("unroll") \
    for (int j_ = 0; j_ < 4; ++j_) { \
        const int sx_ = w * 4 + j_;                    /* = ntile*2 + kstep */ \
        gld16(Wt + ((size_t)kk_ * 128 + (sx_ >> 1) * 16 + mh) * CIN + cb_ \
                 + (sx_ & 1) * 32 + qh * 8, \
              &Bs[(BBUF) * 8192 + sx_ * 512]); \
    } \
} while (0)

#define MFMA_PHASE(ABUF, BBUF) do { \
    __builtin_amdgcn_s_setprio(1); \
    _Pragma("unroll") \
    for (int ks_ = 0; ks_ < 2; ++ks_) { \
        bf16x8 af_[4]; \
        _Pragma("unroll") \
        for (int mt_ = 0; mt_ < 4; ++mt_) \
            af_[mt_] = *(const bf16x8*)&As[(ABUF) * 8192 + aoff[ks_][mt_]]; \
        _Pragma("unroll") \
        for (int nt_ = 0; nt_ < 4; ++nt_) { \
            bf16x8 bf_ = *(const bf16x8*)&Bs[(BBUF) * 8192 + \
                (((wn * 4 + nt_) * 2 + ks_) * 512) + lane * 8]; \
            _Pragma("unroll") \
            for (int mt_ = 0; mt_ < 4; ++mt_) \
                acc[mt_][nt_] = __builtin_amdgcn_mfma_f32_16x16x32_bf16( \
                    af_[mt_], bf_, acc[mt_][nt_], 0, 0, 0); \
        } \
    } \
    __builtin_amdgcn_s_setprio(0); \
} while (0)

#define FENCE() asm volatile("" ::: "memory")

    // One pipeline region (sub-step I of a x6-unrolled body, base SBASE).
    // MFMA is skipped (uniform branch) for steps >= STEPS; issues always
    // happen (clamped) so the vmcnt ledger stays constant.
#define REGION(I, SBASE) do { \
    const int s_ = (SBASE) + (I); \
    lds_sync(); \
    ISSUE_B((I + 1) & 1, s_ + 1);                 FENCE(); \
    ISSUE_A((I + 2) % 3, ix[(I + 2) % 3], s_ + 2); FENCE(); \
    IDXLD(ix[(I + 1) % 3], s_ + 4); \
    asm volatile("s_waitcnt vmcnt(20)" ::: "memory"); \
    __builtin_amdgcn_s_barrier(); \
    FENCE(); \
    if (s_ < STEPS) MFMA_PHASE(I % 3, I & 1); \
} while (0)

    // ---- prologue (B(0) issued BEFORE A(0),A(1) so region 0's vmcnt(20)
    //      ledger matches steady state)
    IDXLD(ix[0], 0);
    IDXLD(ix[1], 1);
    IDXLD(ix[2], 2);
    ISSUE_B(0, 0);            FENCE();
    ISSUE_A(0, ix[0], 0);     FENCE();
    ISSUE_A(1, ix[1], 1);     FENCE();
    IDXLD(ix[0], 3);

    // ---- main loop, x6 unrolled (ring-3 x db-2 period)
#pragma clang loop unroll(disable)
    for (int s = 0; s < STEPS; s += 6) {
        REGION(0, s); REGION(1, s); REGION(2, s);
        REGION(3, s); REGION(4, s); REGION(5, s);
    }
    // drain all remaining (clamped) DMAs before LDS reuse below
    asm volatile("s_waitcnt vmcnt(0)" ::: "memory");
    __builtin_amdgcn_s_barrier();
    FENCE();

    // ---- epilogue: C/D layout col=lane&15, row=(lane>>4)*4+reg
#pragma unroll
    for (int mt = 0; mt < 4; ++mt) {
#pragma unroll
        for (int r4 = 0; r4 < 4; ++r4) {
            int gr = n0 + (wm * 4 + mt) * 16 + qh * 4 + r4;
            if (gr < N) {
#pragma unroll
                for (int nt = 0; nt < 4; ++nt) {
                    float val = acc[mt][nt][r4];
                    size_t off = (size_t)gr * COUT + (wn * 4 + nt) * 16 + mh;
                    if constexpr (OUTF32) ((float*)outv)[off] = val;
                    else                  ((u16*)outv)[off]   = f2b(val);
                }
            }
        }
    }

    // ---- fused per-column BN stats (sum, sumsq) of this block's output
    if constexpr (SSEL >= 0) {
        float sS[4], sQ[4];
#pragma unroll
        for (int nt = 0; nt < 4; ++nt) { sS[nt] = 0.f; sQ[nt] = 0.f; }
#pragma unroll
        for (int mt = 0; mt < 4; ++mt) {
#pragma unroll
            for (int r4 = 0; r4 < 4; ++r4) {
                int gr = n0 + (wm * 4 + mt) * 16 + qh * 4 + r4;
                bool ok = (gr < N);
#pragma unroll
                for (int nt = 0; nt < 4; ++nt) {
                    float v = ok ? acc[mt][nt][r4] : 0.f;
                    sS[nt] += v;
                    sQ[nt] = fmaf(v, v, sQ[nt]);
                }
            }
        }
#pragma unroll
        for (int nt = 0; nt < 4; ++nt) {    // reduce over q = lane>>4
            sS[nt] += __shfl_xor(sS[nt], 16);
            sS[nt] += __shfl_xor(sS[nt], 32);
            sQ[nt] += __shfl_xor(sQ[nt], 16);
            sQ[nt] += __shfl_xor(sQ[nt], 32);
        }
        lds_sync();                         // all MFMA LDS reads done; reuse As
        float* red = (float*)As;            // [4 waves][64 cols] S, then Q
        if (lane < 16) {
#pragma unroll
            for (int nt = 0; nt < 4; ++nt) {
                red[w * 64 + nt * 16 + lane]       = sS[nt];
                red[256 + w * 64 + nt * 16 + lane] = sQ[nt];
            }
        }
        lds_sync();
        if (t < 128) {
            int hi = t >> 6, lo = t & 63;   // waves {hi, hi+2} cover cols hi*64..
            float S = red[hi * 64 + lo] + red[(hi + 2) * 64 + lo];
            float Q = red[256 + hi * 64 + lo] + red[256 + (hi + 2) * 64 + lo];
            atomicAdd(&g_sum[SSEL][t], S);
            atomicAdd(&g_sq[SSEL][t],  Q);
        }
    }
#undef KOFC
#undef CBC
#undef IDXLD
#undef ISSUE_A
#undef ISSUE_B
#undef MFMA_PHASE
#undef FENCE
#undef REGION
}

template<int SEL>
__global__ void finalize_kernel(const void* __restrict__ g, const void* __restrict__ b,
                                float invN)
{
    const bool f32 = (g_f32 != 0);
    int c = threadIdx.x;
    float mu  = g_sum[SEL][c] * invN;
    float var = fmaxf(g_sq[SEL][c] * invN - mu * mu, 0.f);
    float rs  = rsqrtf(var + 1e-5f);
    float sc  = rs * ldf(g, c, f32);
    g_sc[SEL][c] = sc;
    g_sh[SEL][c] = ldf(b, c, f32) - mu * sc;
}

// Gram stats of x: G = X^T X (64x64), colsum = sum_n x[n,:]
__global__ __launch_bounds__(256)
void xstats_kernel(const void* __restrict__ xv, int N)
{
    __shared__ float xs[16 * 64];
    const bool f32 = (g_f32 != 0);
    const int t  = threadIdx.x;
    const int c  = t >> 2;
    const int cb = (t & 3) * 16;
    float acc[16];
#pragma unroll
    for (int j = 0; j < 16; ++j) acc[j] = 0.f;
    float cs = 0.f;

    for (int r0 = blockIdx.x * 16; r0 < N; r0 += gridDim.x * 16) {
        __syncthreads();
        {
            int e = t * 4;
            int rr = e >> 6, qq = e & 63;
            int row = r0 + rr;
            size_t off = (size_t)min(row, N - 1) * 64 + qq;
            bool ok = (row < N);
            float v0, v1, v2, v3;
            if (f32) {
                float4 vv = *(const float4*)((const float*)xv + off);
                v0 = vv.x; v1 = vv.y; v2 = vv.z; v3 = vv.w;
            } else {
                uint2 u = *(const uint2*)((const u16*)xv + off);
                v0 = b2f(u.x & 0xffffu); v1 = b2f(u.x >> 16);
                v2 = b2f(u.y & 0xffffu); v3 = b2f(u.y >> 16);
            }
            xs[e + 0] = ok ? v0 : 0.f;
            xs[e + 1] = ok ? v1 : 0.f;
            xs[e + 2] = ok ? v2 : 0.f;
            xs[e + 3] = ok ? v3 : 0.f;
        }
        __syncthreads();
#pragma unroll
        for (int rr = 0; rr < 16; ++rr) {
            float a = xs[rr * 64 + c];
#pragma unroll
            for (int j = 0; j < 16; ++j)
                acc[j] = fmaf(a, xs[rr * 64 + cb + j], acc[j]);
        }
        if (t < 64) {
#pragma unroll
            for (int rr = 0; rr < 16; ++rr) cs += xs[rr * 64 + t];
        }
    }
#pragma unroll
    for (int j = 0; j < 16; ++j) atomicAdd(&g_G[c * 64 + cb + j], acc[j]);
    if (t < 64) atomicAdd(&g_colsum[t], cs);
}

__global__ __launch_bounds__(128)
void finalize_d_kernel(const void* __restrict__ Wd, const void* __restrict__ gd,
                       const void* __restrict__ bd, float invN)
{
    __shared__ float Gs[64 * 64];
    const bool f32 = (g_f32 != 0);
    const int t = threadIdx.x;
    for (int e = t; e < 4096; e += 128) Gs[e] = g_G[e];
    __syncthreads();
    float w[64];
#pragma unroll
    for (int c = 0; c < 64; ++c) w[c] = ldf(Wd, c * 128 + t, f32);
    float s = 0.f, q = 0.f;
    for (int c = 0; c < 64; ++c) {
        float inner = 0.f;
#pragma unroll 8
        for (int cc = 0; cc < 64; ++cc) inner = fmaf(Gs[c * 64 + cc], w[cc], inner);
        q = fmaf(w[c], inner, q);
        s = fmaf(g_colsum[c], w[c], s);
    }
    float mu  = s * invN;
    float var = fmaxf(q * invN - mu * mu, 0.f);
    float rs  = rsqrtf(var + 1e-5f);
    float sc  = rs * ldf(gd, t, f32);
    g_sc[2][t] = sc;
    g_sh[2][t] = ldf(bd, t, f32) - mu * sc;
}

// out = relu(bn2(out)) + bn_d(x @ Wd), fp32 in/out on d_out
__global__ __launch_bounds__(256)
void finish_dense_kernel(const void* __restrict__ xv, const void* __restrict__ Wdv,
                         float* __restrict__ out, int N)
{
    __shared__ float Xs[64 * 68];
    __shared__ float Ws[64 * COUT];
    const bool f32 = (g_f32 != 0);
    const int t  = threadIdx.x;
    const int tx = t & 31;
    const int ty = t >> 5;
    const int n0 = blockIdx.x * 64;
    const int valid = min(64, N - n0);

    for (int e = t; e < 64 * 16; e += 256) {
        int mm = e >> 4;
        int qq = (e & 15) << 2;
        size_t off = (size_t)min(n0 + mm, N - 1) * 64 + qq;
        float v0, v1, v2, v3;
        if (f32) {
            float4 vv = *(const float4*)((const float*)xv + off);
            v0 = vv.x; v1 = vv.y; v2 = vv.z; v3 = vv.w;
        } else {
            uint2 u = *(const uint2*)((const u16*)xv + off);
            v0 = b2f(u.x & 0xffffu); v1 = b2f(u.x >> 16);
            v2 = b2f(u.y & 0xffffu); v3 = b2f(u.y >> 16);
        }
        *(float4*)&Xs[mm * 68 + qq] = make_float4(v0, v1, v2, v3);
    }
    if (f32) {
        const float* Wp = (const float*)Wdv;
        for (int e = t; e < (64 * COUT) / 8; e += 256) {
            int l = e << 3;
            float4 a = *(const float4*)(Wp + l);
            float4 b = *(const float4*)(Wp + l + 4);
            float* dst = &Ws[l];
            dst[0]=a.x; dst[1]=a.y; dst[2]=a.z; dst[3]=a.w;
            dst[4]=b.x; dst[5]=b.y; dst[6]=b.z; dst[7]=b.w;
        }
    } else {
        const u16* Wp = (const u16*)Wdv;
        for (int e = t; e < (64 * COUT) / 8; e += 256) {
            int l = e << 3;
            uint4 u = *(const uint4*)(Wp + l);
            float* dst = &Ws[l];
            dst[0] = b2f(u.x & 0xffffu); dst[1] = b2f(u.x >> 16);
            dst[2] = b2f(u.y & 0xffffu); dst[3] = b2f(u.y >> 16);
            dst[4] = b2f(u.z & 0xffffu); dst[5] = b2f(u.z >> 16);
            dst[6] = b2f(u.w & 0xffffu); dst[7] = b2f(u.w >> 16);
        }
    }
    __syncthreads();

    float acc[8][4];
#pragma unroll
    for (int mm = 0; mm < 8; ++mm)
#pragma unroll
        for (int j = 0; j < 4; ++j) acc[mm][j] = 0.f;

#pragma unroll 2
    for (int c = 0; c < 64; ++c) {
        float4 wv = *(const float4*)&Ws[c * COUT + tx * 4];
#pragma unroll
        for (int mm = 0; mm < 8; ++mm) {
            float a = Xs[(ty * 8 + mm) * 68 + c];
            acc[mm][0] = fmaf(a, wv.x, acc[mm][0]);
            acc[mm][1] = fmaf(a, wv.y, acc[mm][1]);
            acc[mm][2] = fmaf(a, wv.z, acc[mm][2]);
            acc[mm][3] = fmaf(a, wv.w, acc[mm][3]);
        }
    }

    const int d = tx * 4;
    float s2r[4] = {g_sc[1][d], g_sc[1][d+1], g_sc[1][d+2], g_sc[1][d+3]};
    float h2r[4] = {g_sh[1][d], g_sh[1][d+1], g_sh[1][d+2], g_sh[1][d+3]};
    float sdr[4] = {g_sc[2][d], g_sc[2][d+1], g_sc[2][d+2], g_sc[2][d+3]};
    float hdr[4] = {g_sh[2][d], g_sh[2][d+1], g_sh[2][d+2], g_sh[2][d+3]};
#pragma unroll
    for (int mm = 0; mm < 8; ++mm) {
        int rr = ty * 8 + mm;
        if (rr < valid) {
            float* p = out + (size_t)(n0 + rr) * COUT + d;
            float4 raw = *(float4*)p;
            float o0 = fmaxf(fmaf(raw.x, s2r[0], h2r[0]), 0.f) + fmaf(acc[mm][0], sdr[0], hdr[0]);
            float o1 = fmaxf(fmaf(raw.y, s2r[1], h2r[1]), 0.f) + fmaf(acc[mm][1], sdr[1], hdr[1]);
            float o2 = fmaxf(fmaf(raw.z, s2r[2], h2r[2]), 0.f) + fmaf(acc[mm][2], sdr[2], hdr[2]);
            float o3 = fmaxf(fmaf(raw.w, s2r[3], h2r[3]), 0.f) + fmaf(acc[mm][3], sdr[3], hdr[3]);
            *(float4*)p = make_float4(o0, o1, o2, o3);
        }
    }
}

extern "C" void kernel_launch(void* const* d_in, const int* in_sizes, int n_in,
                              void* d_out, int out_size, void* d_ws, size_t ws_size,
                              hipStream_t stream)
{
    const void* x   = d_in[0];
    const int*  nbr = (const int*)d_in[1];
    const void* W1  = d_in[2];
    const void* g1  = d_in[3];
    const void* b1  = d_in[4];
    const void* W2  = d_in[5];
    const void* g2  = d_in[6];
    const void* b2  = d_in[7];
    const void* Wd  = d_in[8];
    const void* gd  = d_in[9];
    const void* bd  = d_in[10];
    float* out = (float*)d_out;

    const int N = in_sizes[0] / 64;
    u16* tmp = (u16*)d_ws;            // [N,128] bf16 conv1 raw — only ws use
    u16* xb  = (u16*)d_out;           // [N,64] bf16 x — scratch in d_out, dead
                                      // before conv2 overwrites d_out

    const int nbm = (N + 127) / 128;  // MFMA conv blocks (BM=128)
    const int nbf = (N + 63) / 64;    // finish blocks
    const float invN = 1.f / (float)N;

    hipLaunchKernelGGL(probe_zero_kernel, dim3(1), dim3(256), 0, stream,
                       (const u16*)g1, nbr);
    hipLaunchKernelGGL(convert_w_kernel, dim3(1024), dim3(256), 0, stream,
                       W1, W2, x, xb, N);
    // conv1 raw -> tmp (bf16), stats fused (SSEL=0)
    hipLaunchKernelGGL((spconv_mfma<64, false, 1, 0>), dim3(nbm), dim3(256), 0, stream,
                       xb, nbr, tmp, N);
    hipLaunchKernelGGL((finalize_kernel<0>), dim3(1), dim3(128), 0, stream, g1, b1, invN);
    // apply bn1+relu in place so conv2 staging is a pure async copy
    hipLaunchKernelGGL(bn_relu_kernel, dim3(2048), dim3(256), 0, stream, tmp, N);
    // conv2 -> d_out raw fp32, stats fused (SSEL=1)
    hipLaunchKernelGGL((spconv_mfma<128, true, 2, 1>), dim3(nbm), dim3(256), 0, stream,
                       tmp, nbr, out, N);
    hipLaunchKernelGGL((finalize_kernel<1>), dim3(1), dim3(128), 0, stream, g2, b2, invN);
    // dense-branch stats without materializing x@Wd
    hipLaunchKernelGGL(xstats_kernel, dim3(256), dim3(256), 0, stream, x, N);
    hipLaunchKernelGGL(finalize_d_kernel, dim3(1), dim3(128), 0, stream, Wd, gd, bd, invN);
    // out = relu(bn2(out)) + bn_d(x@Wd)
    hipLaunchKernelGGL(finish_dense_kernel, dim3(nbf), dim3(256), 0, stream,
                       x, Wd, out, N);
}